// Round 6
// baseline (192.686 us; speedup 1.0000x reference)
//
#include <hip/hip_runtime.h>

#define NN 19        // nodes
#define NT 4096
#define LAT 512
#define HID 2048
#define NE 342       // edges

// ---------------------------------------------------------------------------
// Build M = I + adjacency-count (19x19) into sM from edge_idx. cnt[] aliases
// scratch LDS. Edge buffer may be int64 (pairs of int32) or int32, detected
// via odd-word check (values in [0,19) => int64 high words all zero).
// ---------------------------------------------------------------------------
__device__ __forceinline__ void build_M(const int* __restrict__ ei, float* sM,
                                        int* scratch, int t, int bs) {
    int* cnt = scratch;
    int* flag = scratch + NN * NN;
    if (t == 0) *flag = 0;
    for (int i = t; i < NN * NN; i += bs) cnt[i] = 0;
    __syncthreads();
    int f = 0;
    for (int i = t; i < NE; i += bs) f |= ei[2 * i + 1];
    if (f) atomicOr(flag, 1);
    __syncthreads();
    const bool i64 = (*flag == 0);
    for (int i = t; i < NE; i += bs) {
        const int s = i64 ? ei[2 * i] : ei[i];
        const int d = i64 ? ei[2 * NE + 2 * i] : ei[NE + i];
        atomicAdd(&cnt[d * NN + s], 1);
    }
    __syncthreads();
    for (int i = t; i < NN * NN; i += bs)
        sM[i] = (float)cnt[i] + ((i / NN) == (i % NN) ? 1.f : 0.f);
    __syncthreads();
}

// ---------------------------------------------------------------------------
// GEMM inner: acc[19][4 cols] over a BK k-slice staged in sA[k*21+i].
// float4 weight loads, 8 in flight (128 B/lane). Writes partial chunk kc.
// ---------------------------------------------------------------------------
template <int BK, int N>
__device__ __forceinline__ void gemm_inner(int col, int kc,
                                           const float* __restrict__ W,
                                           float* __restrict__ part,
                                           const float* __restrict__ sA) {
    const int k0 = kc * BK;
    const float4* __restrict__ w = (const float4*)(W + (size_t)k0 * N + col);
    float4 acc[NN];
#pragma unroll
    for (int i = 0; i < NN; ++i) acc[i] = make_float4(0.f, 0.f, 0.f, 0.f);
#pragma unroll 1
    for (int kk = 0; kk < BK; kk += 8) {
        float4 wb[8];
#pragma unroll
        for (int u = 0; u < 8; ++u) wb[u] = w[(size_t)(kk + u) * (N / 4)];
#pragma unroll
        for (int u = 0; u < 8; ++u) {
#pragma unroll
            for (int i = 0; i < NN; ++i) {
                const float av = sA[(kk + u) * 21 + i];
                acc[i].x = fmaf(av, wb[u].x, acc[i].x);
                acc[i].y = fmaf(av, wb[u].y, acc[i].y);
                acc[i].z = fmaf(av, wb[u].z, acc[i].z);
                acc[i].w = fmaf(av, wb[u].w, acc[i].w);
            }
        }
    }
    float* __restrict__ p = part + (size_t)kc * NN * N + col;
#pragma unroll
    for (int i = 0; i < NN; ++i) *(float4*)(p + (size_t)i * N) = acc[i];
}

// ---------------------------------------------------------------------------
// K1 (fused l1a+l1b): per block kc (32 blocks, 512 threads):
//   build M; h0 = M@z into LDS (transposed, stride 20);
//   h1a k-slice [19x64] = relu((h0 @ W1a[:,k-slice]) + b1a) via 8-way j-split
//   + shfl oct-reduce; then part2[kc] = h1a_slice @ W1b (full N=2048).
// Also zeroes the classifier ticket counter.
// ---------------------------------------------------------------------------
__global__ __launch_bounds__(512) void gemm_l1ab(const float* __restrict__ z,
                                                 const int* __restrict__ ei,
                                                 const float* __restrict__ W1a,
                                                 const float* __restrict__ b1a,
                                                 const float* __restrict__ W1b,
                                                 float* __restrict__ part2,
                                                 unsigned int* __restrict__ counter) {
    __shared__ __align__(16) float h0T[512 * 20];  // [j][i], padded stride 20
    __shared__ __align__(16) float sA[64 * 21];
    __shared__ float sM[NN * NN];
    __shared__ int scratch[NN * NN + 1];
    const int t = threadIdx.x;
    const int kc = blockIdx.x;
    if (kc == 0 && t == 0) *counter = 0u;
    build_M(ei, sM, scratch, t, 512);
    // h0T[j][i] = (M @ z)[i][j]; thread t owns column j = t
    {
        float zv[NN];
#pragma unroll
        for (int s = 0; s < NN; ++s) zv[s] = z[(size_t)s * LAT + t];
#pragma unroll
        for (int i = 0; i < NN; ++i) {
            float a = 0.f;
#pragma unroll
            for (int s = 0; s < NN; ++s) a = fmaf(sM[i * NN + s], zv[s], a);
            h0T[t * 20 + i] = a;
        }
    }
    __syncthreads();
    // h1a slice: c = t>>3 (0..63), jp = t&7; k = kc*64 + c
    {
        const int c = t >> 3, jp = t & 7;
        const int k = kc * 64 + c;
        float acc[NN];
#pragma unroll
        for (int i = 0; i < NN; ++i) acc[i] = 0.f;
#pragma unroll 1
        for (int jj = 0; jj < 64; jj += 8) {
            float wv[8];
#pragma unroll
            for (int u = 0; u < 8; ++u)
                wv[u] = W1a[(size_t)(8 * (jj + u) + jp) * HID + k];
#pragma unroll
            for (int u = 0; u < 8; ++u) {
                const float* hr = h0T + (8 * (jj + u) + jp) * 20;
                const float4 a0 = *(const float4*)(hr);
                const float4 a1 = *(const float4*)(hr + 4);
                const float4 a2 = *(const float4*)(hr + 8);
                const float4 a3 = *(const float4*)(hr + 12);
                const float4 a4 = *(const float4*)(hr + 16);  // .w unused
                const float wu = wv[u];
                acc[0]  = fmaf(a0.x, wu, acc[0]);
                acc[1]  = fmaf(a0.y, wu, acc[1]);
                acc[2]  = fmaf(a0.z, wu, acc[2]);
                acc[3]  = fmaf(a0.w, wu, acc[3]);
                acc[4]  = fmaf(a1.x, wu, acc[4]);
                acc[5]  = fmaf(a1.y, wu, acc[5]);
                acc[6]  = fmaf(a1.z, wu, acc[6]);
                acc[7]  = fmaf(a1.w, wu, acc[7]);
                acc[8]  = fmaf(a2.x, wu, acc[8]);
                acc[9]  = fmaf(a2.y, wu, acc[9]);
                acc[10] = fmaf(a2.z, wu, acc[10]);
                acc[11] = fmaf(a2.w, wu, acc[11]);
                acc[12] = fmaf(a3.x, wu, acc[12]);
                acc[13] = fmaf(a3.y, wu, acc[13]);
                acc[14] = fmaf(a3.z, wu, acc[14]);
                acc[15] = fmaf(a3.w, wu, acc[15]);
                acc[16] = fmaf(a4.x, wu, acc[16]);
                acc[17] = fmaf(a4.y, wu, acc[17]);
                acc[18] = fmaf(a4.z, wu, acc[18]);
            }
        }
#pragma unroll
        for (int i = 0; i < NN; ++i) {
            float v = acc[i];
            v += __shfl_down(v, 1);
            v += __shfl_down(v, 2);
            v += __shfl_down(v, 4);
            if (jp == 0) {
                const float r = v + b1a[k];
                sA[c * 21 + i] = r > 0.f ? r : 0.f;
            }
        }
    }
    __syncthreads();
    gemm_inner<64, HID>(4 * t, kc, W1b, part2, sA);  // 512 threads cover N=2048
}

// K2: part3 = (M @ relu(reduce32(part2)+b1b)) @ W2a.  K=2048, BK=64; grid (4,32)
__global__ __launch_bounds__(256) void gemm_l2a(const float* __restrict__ part2,
                                                const float* __restrict__ b1b,
                                                const int* __restrict__ ei,
                                                const float* __restrict__ W2a,
                                                float* __restrict__ part3) {
    __shared__ __align__(16) float sA[64 * 21];
    __shared__ __align__(16) float sZ[64 * 21];
    __shared__ float sM[NN * NN];
    __shared__ int scratch[NN * NN + 1];
    const int t = threadIdx.x, cb = blockIdx.x, kc = blockIdx.y;
    const int k0 = kc * 64;
    build_M(ei, sM, scratch, t, 256);
    for (int idx = t; idx < NN * 64; idx += 256) {
        const int i = idx / 64, c = idx % 64;
        const int k = k0 + c;
        float s = b1b[k];
#pragma unroll
        for (int cc = 0; cc < 32; ++cc) s += part2[((size_t)cc * NN + i) * HID + k];
        sZ[c * 21 + i] = s > 0.f ? s : 0.f;
    }
    __syncthreads();
    for (int idx = t; idx < NN * 64; idx += 256) {
        const int i = idx / 64, c = idx % 64;
        float acc = 0.f;
#pragma unroll
        for (int s = 0; s < NN; ++s) acc = fmaf(sM[i * NN + s], sZ[c * 21 + s], acc);
        sA[c * 21 + i] = acc;
    }
    __syncthreads();
    gemm_inner<64, NT>(cb * 1024 + 4 * t, kc, W2a, part3, sA);
}

// K3: part4 = relu(reduce32(part3)+b2a) @ W2b.  K=4096, BK=64; grid (4, 64)
__global__ __launch_bounds__(256) void gemm_l2b(const float* __restrict__ part3,
                                                const float* __restrict__ b2a,
                                                const float* __restrict__ W2b,
                                                float* __restrict__ part4) {
    __shared__ __align__(16) float sA[64 * 21];
    const int t = threadIdx.x, cb = blockIdx.x, kc = blockIdx.y;
    const int k0 = kc * 64;
    for (int idx = t; idx < NN * 64; idx += 256) {
        const int i = idx / 64, c = idx % 64;
        const int k = k0 + c;
        float s = b2a[k];
#pragma unroll
        for (int cc = 0; cc < 32; ++cc) s += part3[((size_t)cc * NN + i) * NT + k];
        sA[c * 21 + i] = s > 0.f ? s : 0.f;
    }
    __syncthreads();
    gemm_inner<64, NT>(cb * 1024 + 4 * t, kc, W2b, part4, sA);
}

// ---------------------------------------------------------------------------
// K4: per block (256), k0 = bid*304:
//   flat[k0..k0+304) = reduce64(part4)+b2b  -> out+1 and LDS
//   partC[bid][512] = flat_seg @ Wc1[k0..k0+304)
//   last block (device-scope ticket): reduce partC + bc1, dot Wc2, sigmoid.
// ---------------------------------------------------------------------------
__global__ __launch_bounds__(256) void cls_out_tail(const float* __restrict__ part4,
                                                    const float* __restrict__ b2b,
                                                    const float* __restrict__ Wc1,
                                                    const float* __restrict__ bc1,
                                                    const float* __restrict__ Wc2,
                                                    const float* __restrict__ bc2,
                                                    float* __restrict__ out,
                                                    float* __restrict__ partC,
                                                    unsigned int* __restrict__ counter) {
    __shared__ float sF[304];
    __shared__ __align__(16) float4 comb[128];
    __shared__ float red[128];
    __shared__ int lastFlag;
    const int t = threadIdx.x;
    const int k0 = blockIdx.x * 304;
    float* __restrict__ out1 = out + 1;
    for (int e = t; e < 304; e += 256) {
        const int fidx = k0 + e;
        const int i = fidx >> 12, n = fidx & 4095;
        float s = b2b[n];
#pragma unroll 16
        for (int cc = 0; cc < 64; ++cc) s += part4[((size_t)cc * NN + i) * NT + n];
        sF[e] = s;
        out1[fidx] = s;
    }
    __syncthreads();
    const int q = t & 127, kp = t >> 7;
    const float4* __restrict__ w = (const float4*)Wc1 + (size_t)k0 * 128 + q;
    float4 acc = make_float4(0.f, 0.f, 0.f, 0.f);
#pragma unroll 1
    for (int k = kp; k < 304; k += 16) {
        float4 wb[8];
        float fv[8];
#pragma unroll
        for (int u = 0; u < 8; ++u) wb[u] = w[(size_t)(k + 2 * u) * 128];
#pragma unroll
        for (int u = 0; u < 8; ++u) fv[u] = sF[k + 2 * u];
#pragma unroll
        for (int u = 0; u < 8; ++u) {
            acc.x = fmaf(fv[u], wb[u].x, acc.x);
            acc.y = fmaf(fv[u], wb[u].y, acc.y);
            acc.z = fmaf(fv[u], wb[u].z, acc.z);
            acc.w = fmaf(fv[u], wb[u].w, acc.w);
        }
    }
    if (kp) comb[q] = acc;
    __syncthreads();
    if (!kp) {
        const float4 o = comb[q];
        acc.x += o.x; acc.y += o.y; acc.z += o.z; acc.w += o.w;
        ((float4*)partC)[(size_t)blockIdx.x * 128 + q] = acc;
    }
    __threadfence();  // make partC visible device-wide (cross-XCD)
    __syncthreads();
    if (t == 0) lastFlag = (atomicAdd(counter, 1u) == 255u) ? 1 : 0;
    __syncthreads();
    if (!lastFlag) return;
    __threadfence();  // acquire: invalidate stale cache before reading partC
    // tail: reduce 256 chunks of partC[256][512] (as float4 quads)
    const int half = kp;  // t>>7
    float4 s = make_float4(0.f, 0.f, 0.f, 0.f);
    const float4* __restrict__ pc = (const float4*)partC;
#pragma unroll 8
    for (int c = half * 128; c < half * 128 + 128; ++c) {
        const float4 v = pc[(size_t)c * 128 + q];
        s.x += v.x; s.y += v.y; s.z += v.z; s.w += v.w;
    }
    __syncthreads();  // comb reuse
    if (half) comb[q] = s;
    __syncthreads();
    if (!half) {
        const float4 o = comb[q];
        const float4 b = ((const float4*)bc1)[q];
        const float4 w2 = ((const float4*)Wc2)[q];
        red[t] = (s.x + o.x + b.x) * w2.x + (s.y + o.y + b.y) * w2.y +
                 (s.z + o.z + b.z) * w2.z + (s.w + o.w + b.w) * w2.w;
    }
    __syncthreads();
    for (int off = 64; off > 0; off >>= 1) {
        if (t < off) red[t] += red[t + off];
        __syncthreads();
    }
    if (t == 0) out[0] = 1.f / (1.f + expf(-(red[0] + bc2[0])));
}

extern "C" void kernel_launch(void* const* d_in, const int* in_sizes, int n_in,
                              void* d_out, int out_size, void* d_ws, size_t ws_size,
                              hipStream_t stream) {
    const float* z   = (const float*)d_in[0];
    const int*   ei  = (const int*)d_in[1];
    const float* W1a = (const float*)d_in[2];
    const float* b1a = (const float*)d_in[3];
    const float* W1b = (const float*)d_in[4];
    const float* b1b = (const float*)d_in[5];
    const float* W2a = (const float*)d_in[6];
    const float* b2a = (const float*)d_in[7];
    const float* W2b = (const float*)d_in[8];
    const float* b2b = (const float*)d_in[9];
    const float* Wc1 = (const float*)d_in[10];
    const float* bc1 = (const float*)d_in[11];
    const float* Wc2 = (const float*)d_in[12];
    const float* bc2 = (const float*)d_in[13];
    float* out = (float*)d_out;
    float* ws  = (float*)d_ws;

    // workspace layout (float offsets)
    unsigned int* counter = (unsigned int*)ws;   // ticket, reset by K1 each call
    float* part2 = ws + 1048576;   // 32*19*2048 = 1,245,184
    float* part3 = ws + 2359296;   // 32*19*4096 = 2,490,368
    float* part4 = ws + 4980736;   // 64*19*4096 = 4,980,736
    float* partC = ws + 10485760;  // 256*512    =   131,072

    gemm_l1ab<<<32, 512, 0, stream>>>(z, ei, W1a, b1a, W1b, part2, counter);
    gemm_l2a<<<dim3(4, 32), 256, 0, stream>>>(part2, b1b, ei, W2a, part3);
    gemm_l2b<<<dim3(4, 64), 256, 0, stream>>>(part3, b2a, W2b, part4);
    cls_out_tail<<<256, 256, 0, stream>>>(part4, b2b, Wc1, bc1, Wc2, bc2,
                                          out, partC, counter);
}